// Round 7
// baseline (9362.782 us; speedup 1.0000x reference)
//
#include <hip/hip_runtime.h>
#include <hip/hip_bf16.h>

typedef __hip_bfloat16 bf16;
typedef __attribute__((ext_vector_type(8))) short short8;
typedef __attribute__((ext_vector_type(4))) float f32x4;

#define N_ 8
#define B_ 64
#define T_ 256
#define IN_ 64
#define H_ 512
#define G4_ 2048
#define M_ 512
#define O_ 7

__device__ __forceinline__ float sigf(float x) { return 1.0f / (1.0f + __expf(-x)); }
__device__ __forceinline__ float tanhfast(float x) { return 2.0f / (1.0f + __expf(-2.0f * x)) - 1.0f; }

// ---------------- convert fp32 -> bf16 ----------------
__global__ void cvt_kernel(const float* __restrict__ src, bf16* __restrict__ dst, int n4) {
  for (int i = blockIdx.x * blockDim.x + threadIdx.x; i < n4; i += gridDim.x * blockDim.x) {
    float4 v = ((const float4*)src)[i];
    bf16 t0 = __float2bfloat16(v.x), t1 = __float2bfloat16(v.y);
    bf16 t2 = __float2bfloat16(v.z), t3 = __float2bfloat16(v.w);
    ushort4 o;
    o.x = *(unsigned short*)&t0; o.y = *(unsigned short*)&t1;
    o.z = *(unsigned short*)&t2; o.w = *(unsigned short*)&t3;
    ((ushort4*)dst)[i] = o;
  }
}

// ---------------- K1: z = leaky(x@Win^T + bin)*10 ----------------
__global__ void input_kernel(const float* __restrict__ x, const float* __restrict__ Win,
                             const float* __restrict__ bin, bf16* __restrict__ z) {
  int bid = blockIdx.x;
  int t = bid >> 6;
  int b = bid & 63;
  __shared__ float xr[IN_];
  int tid = threadIdx.x;
  if (tid < IN_) xr[tid] = x[((size_t)b * T_ + t) * IN_ + tid];
  __syncthreads();
  for (int h = tid; h < H_; h += 256) {
    const float* w = Win + (size_t)h * IN_;
    float s = bin[h];
#pragma unroll 16
    for (int i = 0; i < IN_; ++i) s += xr[i] * w[i];
    s = (s > 0.f ? s : 0.2f * s) * 10.f;
    z[((size_t)t * B_ + b) * H_ + h] = __float2bfloat16(s);
  }
}

// ---------------- K2: persistent weight-stationary LSTM scan + fused head ----------------
// 256 blocks x 512 thr, 1 block/CU. Block (n, ub): 16 hidden/M units of model n.
// NEW role map: m = w>>2 (waves 0-3: ih-matrix, 4-7: hh-matrix), g = w&3.
//   -> each SIMD pairs one ih-wave with one hh-wave (balanced phases).
// Superstep s: L0(t=s), L1(t=s-1), H1(t=s-2), H2(t=s-3).
//
// SHADOW z-matmul: the L0 ih-part (z@Wih0) depends on NO cross-block data.
// Waves 0-3 compute it for t=s+1 into registers DURING the poll window
// (after flag post, BEFORE the acquire fence) -> loads hit warm L2 and the
// work absorbs straggler skew. Phase A just dumps registers to S0.
// Poll runs on wave 7 (no shadow work); H2 on waves 4/5.
//
// Sync protocol: EXACTLY R3/R6's proven one (sc1 write-through relaxed stores
// for h/mstage, relaxed flag store after vmcnt-draining barrier, relaxed sc1
// poll, one agent acquire fence per superstep). Flags packed per model
// (32 x 4B dwords) so each poll iteration touches 2 lines, not 32.
__global__ void __launch_bounds__(512, 2) scan_kernel(
    const bf16* __restrict__ z,
    const bf16* __restrict__ Wih0, const bf16* __restrict__ Whh0,
    const float* __restrict__ bih0, const float* __restrict__ bhh0,
    const bf16* __restrict__ Wih1, const bf16* __restrict__ Whh1,
    const float* __restrict__ bih1, const float* __restrict__ bhh1,
    const bf16* __restrict__ Wh1, const float* __restrict__ bh1,
    const float* __restrict__ Wh2, const float* __restrict__ bh2,
    bf16* __restrict__ h0buf, bf16* __restrict__ h1buf,
    bf16* __restrict__ mstage, float* __restrict__ out,
    unsigned* __restrict__ flags)
{
  __shared__ float S0[8][B_][16];   // slots: gate g ih -> g, hh -> 4+g
  __shared__ float S1[8][B_][16];
  __shared__ float c0s[B_ * 16];
  __shared__ float c1s[B_ * 16];
  __shared__ bf16 wh1s[16][H_ + 4]; // block's 16 Wh1 rows, padded (16.1KB)

  const int tid = threadIdx.x;
  const int lane = tid & 63;
  const int w = tid >> 6;      // 0..7
  const int m = w >> 2;        // 0: ih-matrix (shadow waves), 1: hh-matrix
  const int g = w & 3;         // gate 0..3 (i,f,g,o)
  const int q = lane >> 4;
  const int cl = lane & 15;
  const int bid = blockIdx.x;
  const int n = bid >> 5;
  const int blk = bid & 31;
  const int ub = blk << 4;

  const size_t NBH = (size_t)N_ * B_ * H_;
  const size_t NBM = (size_t)N_ * B_ * M_;

  // ---- one-time weight preload into registers ----
  const size_t wrow = (size_t)n * G4_ * H_ + (size_t)(g * H_ + ub + cl) * H_ + q * 8;
  const bf16* WL0 = (m == 0 ? Wih0 : Whh0) + wrow;
  const bf16* WL1 = (m == 0 ? Wih1 : Whh1) + wrow;
  short8 wl0[16], wl1[16];
#pragma unroll
  for (int kk = 0; kk < 16; ++kk) {
    wl0[kk] = *(const short8*)(WL0 + kk * 32);
    wl1[kk] = *(const short8*)(WL1 + kk * 32);
  }
  // bias carried by the ih wave of each gate
  const int bi = n * G4_ + g * H_ + ub + cl;
  const float bs0 = (m == 0) ? (bih0[bi] + bhh0[bi]) : 0.f;
  const float bs1 = (m == 0) ? (bih1[bi] + bhh1[bi]) : 0.f;
  const float bh1v = bh1[n * M_ + ub + cl];   // H1 bias (waves 0..3 use it)

  // ---- one-time Wh1 -> LDS ----
  {
    const bf16* wsrc = Wh1 + (size_t)n * M_ * H_ + (size_t)ub * H_;
    for (int i = tid; i < 16 * 64; i += 512) {
      int row = i >> 6, c8 = (i & 63) * 8;
      *(short8*)&wh1s[row][c8] = *(const short8*)(wsrc + (size_t)row * H_ + c8);
    }
  }

  for (int e = tid; e < B_ * 16; e += 512) { c0s[e] = 0.f; c1s[e] = 0.f; }
  __syncthreads();   // wh1s + c-state ready

  // packed flags: model n occupies flags[n*64 .. n*64+31] (dwords)
  unsigned* myflag   = flags + (size_t)n * 64 + blk;
  unsigned* pollbase = flags + (size_t)n * 64;

  // ---- prologue: shadow z-partial for t=0 (ih waves) ----
  f32x4 zacc[4];
  if (m == 0) {
#pragma unroll
    for (int strip = 0; strip < 4; ++strip) {
      zacc[strip] = (f32x4){bs0, bs0, bs0, bs0};
      const bf16* Ap = z + (size_t)(strip * 16 + cl) * H_ + q * 8;
#pragma unroll
      for (int kk = 0; kk < 16; ++kk) {
        short8 a = *(const short8*)(Ap + kk * 32);
        zacc[strip] = __builtin_amdgcn_mfma_f32_16x16x32_bf16(a, wl0[kk], zacc[strip], 0, 0, 0);
      }
    }
  }

  for (int s = 0; s < T_ + 3; ++s) {
    const bool doL0 = (s < T_);
    const bool doL1 = (s >= 1 && s <= T_);
    const bool doH1 = (s >= 2 && s <= T_ + 1);
    const bool doH2 = (s >= 3);

    // ---- phase A ----
    if (doL0) {
      if (m == 0) {
        // dump precomputed z-partial (computed in last superstep's shadow)
#pragma unroll
        for (int strip = 0; strip < 4; ++strip)
#pragma unroll
          for (int r = 0; r < 4; ++r)
            S0[g][strip * 16 + q * 4 + r][cl] = zacc[strip][r];
      } else {
        // L0 hh-part: A = h0(s-1)
        const bf16* A = h0buf + (size_t)((s & 1) ^ 1) * NBH + (size_t)n * B_ * H_;
#pragma unroll
        for (int strip = 0; strip < 4; ++strip) {
          f32x4 acc = (f32x4){0.f, 0.f, 0.f, 0.f};
          const bf16* Ap = A + (size_t)(strip * 16 + cl) * H_ + q * 8;
#pragma unroll
          for (int kk = 0; kk < 16; ++kk) {
            short8 a = *(const short8*)(Ap + kk * 32);
            acc = __builtin_amdgcn_mfma_f32_16x16x32_bf16(a, wl0[kk], acc, 0, 0, 0);
          }
#pragma unroll
          for (int r = 0; r < 4; ++r) S0[4 + g][strip * 16 + q * 4 + r][cl] = acc[r];
        }
      }
    }
    // ---- L1 MFMA (both matrices) ----
    if (doL1) {
      const int t = s - 1;
      const bf16* A = (m == 0)
          ? h0buf + (size_t)(t & 1) * NBH + (size_t)n * B_ * H_
          : h1buf + (size_t)((t & 1) ^ 1) * NBH + (size_t)n * B_ * H_;
#pragma unroll
      for (int strip = 0; strip < 4; ++strip) {
        f32x4 acc = (f32x4){bs1, bs1, bs1, bs1};
        const bf16* Ap = A + (size_t)(strip * 16 + cl) * H_ + q * 8;
#pragma unroll
        for (int kk = 0; kk < 16; ++kk) {
          short8 a = *(const short8*)(Ap + kk * 32);
          acc = __builtin_amdgcn_mfma_f32_16x16x32_bf16(a, wl1[kk], acc, 0, 0, 0);
        }
#pragma unroll
        for (int r = 0; r < 4; ++r) S1[4 * m + g][strip * 16 + q * 4 + r][cl] = acc[r];
      }
    }
    // ---- H1: 16 M-units of leaky(h1(s-2)@Wh1^T + bh1), waves 0..3 ----
    if (doH1 && w < 4) {
      const int tH1 = s - 2;
      f32x4 aH = (f32x4){bh1v, bh1v, bh1v, bh1v};
      const bf16* hsrc = h1buf + (size_t)(tH1 & 1) * NBH + (size_t)n * B_ * H_;
      const int ar = (w * 16 + cl) * H_ + q * 8;
      for (int kk = 0; kk < H_; kk += 32) {
        short8 a = *(const short8*)(hsrc + ar + kk);
        short8 b = *(const short8*)&wh1s[cl][q * 8 + kk];
        aH = __builtin_amdgcn_mfma_f32_16x16x32_bf16(a, b, aH, 0, 0, 0);
      }
      bf16* msl = mstage + (size_t)(tH1 & 3) * NBM + (size_t)n * B_ * M_;
#pragma unroll
      for (int r = 0; r < 4; ++r) {
        float v = aH[r];
        v = v > 0.f ? v : 0.2f * v;
        bf16 vb = __float2bfloat16(v);
        unsigned hb = *(unsigned short*)&vb;
        unsigned nb = (unsigned)__shfl_xor((int)hb, 1, 64);  // partner lane cl^1
        if (!(cl & 1)) {
          unsigned word = hb | (nb << 16);
          __hip_atomic_store((unsigned*)(msl + (w * 16 + q * 4 + r) * M_ + ub + cl),
                             word, __ATOMIC_RELAXED, __HIP_MEMORY_SCOPE_AGENT);
        }
      }
    }

    __syncthreads();

    // ---- elementwise: assemble gates (ih slot g + hh slot 4+g), update c, write h ----
    if (doL0) {
      bf16* h0out = h0buf + (size_t)(s & 1) * NBH + (size_t)n * B_ * H_;
      for (int e = tid; e < B_ * 16; e += 512) {
        int row = e >> 4, ul = e & 15;
        float gi = S0[0][row][ul] + S0[4][row][ul];
        float gf = S0[1][row][ul] + S0[5][row][ul];
        float gg = S0[2][row][ul] + S0[6][row][ul];
        float go = S0[3][row][ul] + S0[7][row][ul];
        float c = c0s[e];
        float cn = sigf(gf) * c + sigf(gi) * tanhfast(gg);
        c0s[e] = cn;
        float hv = sigf(go) * tanhfast(cn);
        bf16 hb16 = __float2bfloat16(hv);
        unsigned hb = *(unsigned short*)&hb16;
        unsigned nb = (unsigned)__shfl_xor((int)hb, 1, 64);  // partner tid^1 = ul^1
        if (!(ul & 1)) {
          unsigned word = hb | (nb << 16);
          __hip_atomic_store((unsigned*)(h0out + row * H_ + ub + ul), word,
                             __ATOMIC_RELAXED, __HIP_MEMORY_SCOPE_AGENT);
        }
      }
    }
    if (doL1) {
      const int t = s - 1;
      bf16* h1out = h1buf + (size_t)(t & 1) * NBH + (size_t)n * B_ * H_;
      for (int e = tid; e < B_ * 16; e += 512) {
        int row = e >> 4, ul = e & 15;
        float gi = S1[0][row][ul] + S1[4][row][ul];
        float gf = S1[1][row][ul] + S1[5][row][ul];
        float gg = S1[2][row][ul] + S1[6][row][ul];
        float go = S1[3][row][ul] + S1[7][row][ul];
        float c = c1s[e];
        float cn = sigf(gf) * c + sigf(gi) * tanhfast(gg);
        c1s[e] = cn;
        float hv = sigf(go) * tanhfast(cn);
        bf16 hb16 = __float2bfloat16(hv);
        unsigned hb = *(unsigned short*)&hb16;
        unsigned nb = (unsigned)__shfl_xor((int)hb, 1, 64);
        if (!(ul & 1)) {
          unsigned word = hb | (nb << 16);
          __hip_atomic_store((unsigned*)(h1out + row * H_ + ub + ul), word,
                             __ATOMIC_RELAXED, __HIP_MEMORY_SCOPE_AGENT);
        }
      }
    }

    // __syncthreads drains vmcnt(0) across all waves -> every sc1 data store
    // has reached the coherence point before the flag store issues.
    __syncthreads();
    if (tid == 0)
      __hip_atomic_store(myflag, (unsigned)(s + 1), __ATOMIC_RELAXED,
                         __HIP_MEMORY_SCOPE_AGENT);

    // ================= barrier shadow =================
    // H2 (waves 4,5): reads mstage slot (s-3)&3, published superstep s-1.
    if (doH2 && (w == 4 || w == 5)) {
      const int tH2 = s - 3;
      const int b = blk * 2 + (w - 4);
      const int o = lane & 7;
      const int oc = o < 7 ? o : 0;
      const int mc = (lane >> 3) * 64;
      const bf16* ms = mstage + (size_t)(tH2 & 3) * NBM + ((size_t)n * B_ + b) * M_ + mc;
      const float* w2p = Wh2 + (size_t)n * O_ * M_ + (size_t)oc * M_ + mc;
      float p = 0.f;
#pragma unroll
      for (int j = 0; j < 64; j += 8) {
        short8 av = *(const short8*)(ms + j);
        const bf16* ae = (const bf16*)&av;
        float4 w0 = *(const float4*)(w2p + j);
        float4 w1 = *(const float4*)(w2p + j + 4);
        p += (float)ae[0] * w0.x + (float)ae[1] * w0.y + (float)ae[2] * w0.z + (float)ae[3] * w0.w
           + (float)ae[4] * w1.x + (float)ae[5] * w1.y + (float)ae[6] * w1.z + (float)ae[7] * w1.w;
      }
      p += __shfl_xor(p, 8, 64);
      p += __shfl_xor(p, 16, 64);
      p += __shfl_xor(p, 32, 64);
      if (lane < 7) {
        p += bh2[n * O_ + o];
        out[(((size_t)n * B_ + b) * T_ + tH2) * O_ + o] = p;
      }
    }

    // shadow z-matmul (waves 0-3): z@Wih0 partial for t=s+1, pure read-only
    // input, loads hit warm (pre-fence) L2; result survives in registers.
    if (m == 0 && s + 1 < T_) {
      const bf16* A = z + (size_t)(s + 1) * B_ * H_;
#pragma unroll
      for (int strip = 0; strip < 4; ++strip) {
        zacc[strip] = (f32x4){bs0, bs0, bs0, bs0};
        const bf16* Ap = A + (size_t)(strip * 16 + cl) * H_ + q * 8;
#pragma unroll
        for (int kk = 0; kk < 16; ++kk) {
          short8 a = *(const short8*)(Ap + kk * 32);
          zacc[strip] = __builtin_amdgcn_mfma_f32_16x16x32_bf16(a, wl0[kk], zacc[strip], 0, 0, 0);
        }
      }
    }

    // ---- consumer: wave 7 (no shadow work) polls the model's packed flags ----
    if (w == 7) {
      const unsigned tgt = (unsigned)(s + 1);
      unsigned* fp = pollbase + (lane & 31);
      int spins = 0;
      while (__hip_atomic_load(fp, __ATOMIC_RELAXED, __HIP_MEMORY_SCOPE_AGENT) < tgt) {
        __builtin_amdgcn_s_sleep(2);
        if (++spins >= 64) {
          spins = 0;
          __builtin_amdgcn_fence(__ATOMIC_ACQUIRE, "agent");
        }
      }
      __builtin_amdgcn_fence(__ATOMIC_ACQUIRE, "agent");
    }
    __syncthreads();
  }
}

extern "C" void kernel_launch(void* const* d_in, const int* in_sizes, int n_in,
                              void* d_out, int out_size, void* d_ws, size_t ws_size,
                              hipStream_t stream) {
  (void)in_sizes; (void)n_in; (void)out_size; (void)ws_size;
  const float* x    = (const float*)d_in[0];
  const float* Win  = (const float*)d_in[1];
  const float* bin  = (const float*)d_in[2];
  const float* Wih0 = (const float*)d_in[3];
  const float* Whh0 = (const float*)d_in[4];
  const float* bih0 = (const float*)d_in[5];
  const float* bhh0 = (const float*)d_in[6];
  const float* Wih1 = (const float*)d_in[7];
  const float* Whh1 = (const float*)d_in[8];
  const float* bih1 = (const float*)d_in[9];
  const float* bhh1 = (const float*)d_in[10];
  const float* Wh1  = (const float*)d_in[11];
  const float* bh1  = (const float*)d_in[12];
  const float* Wh2  = (const float*)d_in[13];
  const float* bh2  = (const float*)d_in[14];

  const size_t WLSTM = (size_t)N_ * G4_ * H_;
  const size_t WH1   = (size_t)N_ * M_ * H_;
  const size_t NFLAG = (size_t)N_ * 64;   // packed: 32 dwords used per model

  char* ws = (char*)d_ws;
  size_t off = 0;
  bf16* z      = (bf16*)(ws + off); off += (size_t)T_ * B_ * H_ * sizeof(bf16);
  bf16* Wih0b  = (bf16*)(ws + off); off += WLSTM * sizeof(bf16);
  bf16* Whh0b  = (bf16*)(ws + off); off += WLSTM * sizeof(bf16);
  bf16* Wih1b  = (bf16*)(ws + off); off += WLSTM * sizeof(bf16);
  bf16* Whh1b  = (bf16*)(ws + off); off += WLSTM * sizeof(bf16);
  bf16* Wh1b   = (bf16*)(ws + off); off += WH1 * sizeof(bf16);
  bf16* h0buf  = (bf16*)(ws + off); off += 2 * (size_t)N_ * B_ * H_ * sizeof(bf16);
  bf16* h1buf  = (bf16*)(ws + off); off += 2 * (size_t)N_ * B_ * H_ * sizeof(bf16);
  bf16* mstage = (bf16*)(ws + off); off += 4 * (size_t)N_ * B_ * M_ * sizeof(bf16);
  unsigned* flags = (unsigned*)(ws + off); off += NFLAG * sizeof(unsigned);

  // zero h/m state + flags (contiguous span)
  hipMemsetAsync(h0buf, 0, (char*)(flags + NFLAG) - (char*)h0buf, stream);

  cvt_kernel<<<dim3(2048), dim3(256), 0, stream>>>(Wih0, Wih0b, (int)(WLSTM / 4));
  cvt_kernel<<<dim3(2048), dim3(256), 0, stream>>>(Whh0, Whh0b, (int)(WLSTM / 4));
  cvt_kernel<<<dim3(2048), dim3(256), 0, stream>>>(Wih1, Wih1b, (int)(WLSTM / 4));
  cvt_kernel<<<dim3(2048), dim3(256), 0, stream>>>(Whh1, Whh1b, (int)(WLSTM / 4));
  cvt_kernel<<<dim3(1024), dim3(256), 0, stream>>>(Wh1, Wh1b, (int)(WH1 / 4));

  input_kernel<<<dim3(T_ * B_), dim3(256), 0, stream>>>(x, Win, bin, z);

  scan_kernel<<<dim3(256), dim3(512), 0, stream>>>(
      z, Wih0b, Whh0b, bih0, bhh0, Wih1b, Whh1b, bih1, bhh1,
      Wh1b, bh1, Wh2, bh2, h0buf, h1buf, mstage, (float*)d_out, flags);
}

// Round 8
// 4849.463 us; speedup vs baseline: 1.9307x; 1.9307x over previous
//
#include <hip/hip_runtime.h>
#include <hip/hip_bf16.h>

typedef __hip_bfloat16 bf16;
typedef __attribute__((ext_vector_type(8))) short short8;
typedef __attribute__((ext_vector_type(4))) float f32x4;

#define N_ 8
#define B_ 64
#define T_ 256
#define IN_ 64
#define H_ 512
#define G4_ 2048
#define M_ 512
#define O_ 7
#define HP 520   // padded LDS row stride (bf16): 1040B = 65 x 16B chunks -> odd k, balanced banks

__device__ __forceinline__ float sigf(float x) { return 1.0f / (1.0f + __expf(-x)); }
__device__ __forceinline__ float tanhfast(float x) { return 2.0f / (1.0f + __expf(-2.0f * x)) - 1.0f; }
__device__ __forceinline__ float bfbits2f(unsigned short u) { return __uint_as_float(((unsigned)u) << 16); }

// ---------------- convert fp32 -> bf16 ----------------
__global__ void cvt_kernel(const float* __restrict__ src, bf16* __restrict__ dst, int n4) {
  for (int i = blockIdx.x * blockDim.x + threadIdx.x; i < n4; i += gridDim.x * blockDim.x) {
    float4 v = ((const float4*)src)[i];
    bf16 t0 = __float2bfloat16(v.x), t1 = __float2bfloat16(v.y);
    bf16 t2 = __float2bfloat16(v.z), t3 = __float2bfloat16(v.w);
    ushort4 o;
    o.x = *(unsigned short*)&t0; o.y = *(unsigned short*)&t1;
    o.z = *(unsigned short*)&t2; o.w = *(unsigned short*)&t3;
    ((ushort4*)dst)[i] = o;
  }
}

// ---------------- K1: z = leaky(x@Win^T + bin)*10 ----------------
__global__ void input_kernel(const float* __restrict__ x, const float* __restrict__ Win,
                             const float* __restrict__ bin, bf16* __restrict__ z) {
  int bid = blockIdx.x;
  int t = bid >> 6;
  int b = bid & 63;
  __shared__ float xr[IN_];
  int tid = threadIdx.x;
  if (tid < IN_) xr[tid] = x[((size_t)b * T_ + t) * IN_ + tid];
  __syncthreads();
  for (int h = tid; h < H_; h += 256) {
    const float* w = Win + (size_t)h * IN_;
    float s = bin[h];
#pragma unroll 16
    for (int i = 0; i < IN_; ++i) s += xr[i] * w[i];
    s = (s > 0.f ? s : 0.2f * s) * 10.f;
    z[((size_t)t * B_ + b) * H_ + h] = __float2bfloat16(s);
  }
}

// stage a [64][512] bf16 slab from global into LDS [64][HP] via DEVICE-SCOPE
// (sc1, MALL-direct) loads: always coherent with producers' sc1 stores, no
// acquire fence needed, XCD L2 never invalidated. All 16 loads issue before
// the first ds_write waits (batched arrays -> full MLP).
__device__ __forceinline__ void stage_slab(const bf16* __restrict__ src,
                                           bf16 (*hs)[HP], int tid) {
  unsigned long long va[8], vb[8];
#pragma unroll
  for (int it = 0; it < 8; ++it) {
    int i = tid + it * 512;
    int row = i >> 6, c16 = (i & 63) * 8;
    const unsigned long long* gp = (const unsigned long long*)(src + (size_t)row * H_ + c16);
    va[it] = __hip_atomic_load(gp, __ATOMIC_RELAXED, __HIP_MEMORY_SCOPE_AGENT);
    vb[it] = __hip_atomic_load(gp + 1, __ATOMIC_RELAXED, __HIP_MEMORY_SCOPE_AGENT);
  }
#pragma unroll
  for (int it = 0; it < 8; ++it) {
    int i = tid + it * 512;
    int row = i >> 6, c16 = (i & 63) * 8;
    unsigned long long* lp = (unsigned long long*)&hs[row][c16];
    lp[0] = va[it]; lp[1] = vb[it];
  }
}

// ---------------- K2: persistent weight-stationary LSTM scan + fused head ----------------
// 256 blocks x 512 thr, 1 block/CU. Block (n, ub): 16 hidden/M units of model n.
// Waves: m = w>>2 (0: ih-group, 1: hh-group), g = w&3 -> each SIMD pairs ih+hh.
// Superstep s: L0(t=s), L1(t=s-1), H1(t=s-2), H2(t=s-3). 5 phases:
//   P1 stage hs=h0(s-1) | P2 L0-ih(z,cached)+L0-hh(hs)+L1-ih(hs) | P3 EW-L0 +
//   restage hs=h1(s-2) | P4 L1-hh(hs)+H1(hs,wh1s) | P5 EW-L1; flag; shadow H2+poll.
//
// NO acquire fence anywhere in the loop: cross-block data (h slabs, mstage) is
// read with device-scope sc1 loads (MALL-direct, coherent with the proven sc1
// write-through producer stores). L2 stays permanently hot for z/Wh1/Wh2.
// c-state lives in registers (thread<->unit map is static across supersteps).
__global__ void __launch_bounds__(512, 2) scan_kernel(
    const bf16* __restrict__ z,
    const bf16* __restrict__ Wih0, const bf16* __restrict__ Whh0,
    const float* __restrict__ bih0, const float* __restrict__ bhh0,
    const bf16* __restrict__ Wih1, const bf16* __restrict__ Whh1,
    const float* __restrict__ bih1, const float* __restrict__ bhh1,
    const bf16* __restrict__ Wh1, const float* __restrict__ bh1,
    const float* __restrict__ Wh2, const float* __restrict__ bh2,
    bf16* __restrict__ h0buf, bf16* __restrict__ h1buf,
    bf16* __restrict__ mstage, float* __restrict__ out,
    unsigned* __restrict__ flags)
{
  __shared__ float S0[8][B_][16];   // gate g: ih -> slot g, hh -> slot 4+g
  __shared__ float S1[8][B_][16];
  __shared__ bf16 hs[B_][HP];       // staged h-slab (h0(s-1) in P1/P2, h1(s-2) in P3/P4)
  __shared__ bf16 wh1s[16][HP];     // block's 16 Wh1 rows

  const int tid = threadIdx.x;
  const int lane = tid & 63;
  const int w = tid >> 6;      // 0..7
  const int m = w >> 2;        // 0: ih-group, 1: hh-group
  const int g = w & 3;         // gate 0..3 (i,f,g,o)
  const int q = lane >> 4;
  const int cl = lane & 15;
  const int bid = blockIdx.x;
  const int n = bid >> 5;
  const int blk = bid & 31;
  const int ub = blk << 4;

  const size_t NBH = (size_t)N_ * B_ * H_;
  const size_t NBM = (size_t)N_ * B_ * M_;

  // ---- one-time weight preload into registers ----
  const size_t wrow = (size_t)n * G4_ * H_ + (size_t)(g * H_ + ub + cl) * H_ + q * 8;
  const bf16* WL0 = (m == 0 ? Wih0 : Whh0) + wrow;
  const bf16* WL1 = (m == 0 ? Wih1 : Whh1) + wrow;
  short8 wl0[16], wl1[16];
#pragma unroll
  for (int kk = 0; kk < 16; ++kk) {
    wl0[kk] = *(const short8*)(WL0 + kk * 32);
    wl1[kk] = *(const short8*)(WL1 + kk * 32);
  }
  const int bi = n * G4_ + g * H_ + ub + cl;
  const float bs0 = (m == 0) ? (bih0[bi] + bhh0[bi]) : 0.f;
  const float bs1 = (m == 0) ? (bih1[bi] + bhh1[bi]) : 0.f;
  const float bh1v = bh1[n * M_ + ub + cl];   // H1 bias (ih waves)

  // ---- one-time Wh1 -> LDS ----
  {
    const bf16* wsrc = Wh1 + (size_t)n * M_ * H_ + (size_t)ub * H_;
    for (int i = tid; i < 16 * 64; i += 512) {
      int row = i >> 6, c8 = (i & 63) * 8;
      *(short8*)&wh1s[row][c8] = *(const short8*)(wsrc + (size_t)row * H_ + c8);
    }
  }
  // c-state in registers: thread handles units e=tid and e=tid+512 forever
  float c0r0 = 0.f, c0r1 = 0.f, c1r0 = 0.f, c1r1 = 0.f;
  __syncthreads();

  // packed flags: model n occupies flags[n*64 .. n*64+31]
  unsigned* myflag   = flags + (size_t)n * 64 + blk;
  unsigned* pollbase = flags + (size_t)n * 64;

  for (int s = 0; s < T_ + 3; ++s) {
    const bool doL0 = (s < T_);
    const bool doL1 = (s >= 1 && s <= T_);
    const bool doH1 = (s >= 2 && s <= T_ + 1);
    const bool doH2 = (s >= 3);

    // ---- P1: stage hs = h0(s-1) (zeros at s=0 via memset) ----
    if (s <= T_)
      stage_slab(h0buf + (size_t)((s & 1) ^ 1) * NBH + (size_t)n * B_ * H_, hs, tid);
    __syncthreads();

    // ---- P2: L0 (ih from z cached, hh from hs) + L1-ih (hs) ----
    if (doL0) {
      if (m == 0) {
        const bf16* A = z + (size_t)s * B_ * H_;
#pragma unroll
        for (int strip = 0; strip < 4; ++strip) {
          f32x4 acc = (f32x4){bs0, bs0, bs0, bs0};
          const bf16* Ap = A + (size_t)(strip * 16 + cl) * H_ + q * 8;
#pragma unroll
          for (int kk = 0; kk < 16; ++kk) {
            short8 a = *(const short8*)(Ap + kk * 32);
            acc = __builtin_amdgcn_mfma_f32_16x16x32_bf16(a, wl0[kk], acc, 0, 0, 0);
          }
#pragma unroll
          for (int r = 0; r < 4; ++r) S0[g][strip * 16 + q * 4 + r][cl] = acc[r];
        }
      } else {
#pragma unroll
        for (int strip = 0; strip < 4; ++strip) {
          f32x4 acc = (f32x4){0.f, 0.f, 0.f, 0.f};
#pragma unroll
          for (int kk = 0; kk < 16; ++kk) {
            short8 a = *(const short8*)&hs[strip * 16 + cl][q * 8 + kk * 32];
            acc = __builtin_amdgcn_mfma_f32_16x16x32_bf16(a, wl0[kk], acc, 0, 0, 0);
          }
#pragma unroll
          for (int r = 0; r < 4; ++r) S0[4 + g][strip * 16 + q * 4 + r][cl] = acc[r];
        }
      }
    }
    if (doL1 && m == 0) {   // L1-ih: A = h0(s-1) = hs
#pragma unroll
      for (int strip = 0; strip < 4; ++strip) {
        f32x4 acc = (f32x4){bs1, bs1, bs1, bs1};
#pragma unroll
        for (int kk = 0; kk < 16; ++kk) {
          short8 a = *(const short8*)&hs[strip * 16 + cl][q * 8 + kk * 32];
          acc = __builtin_amdgcn_mfma_f32_16x16x32_bf16(a, wl1[kk], acc, 0, 0, 0);
        }
#pragma unroll
        for (int r = 0; r < 4; ++r) S1[g][strip * 16 + q * 4 + r][cl] = acc[r];
      }
    }
    __syncthreads();

    // ---- P3: restage hs = h1(s-2) ; EW-L0 -> h0(s) sc1 stores ----
    if (s >= 1 && s <= T_ + 1)
      stage_slab(h1buf + (size_t)(s & 1) * NBH + (size_t)n * B_ * H_, hs, tid);
    if (doL0) {
      bf16* h0out = h0buf + (size_t)(s & 1) * NBH + (size_t)n * B_ * H_;
#pragma unroll
      for (int it = 0; it < 2; ++it) {
        int e = tid + it * 512;
        int row = e >> 4, ul = e & 15;
        float gi = S0[0][row][ul] + S0[4][row][ul];
        float gf = S0[1][row][ul] + S0[5][row][ul];
        float gg = S0[2][row][ul] + S0[6][row][ul];
        float go = S0[3][row][ul] + S0[7][row][ul];
        float c = it ? c0r1 : c0r0;
        float cn = sigf(gf) * c + sigf(gi) * tanhfast(gg);
        if (it) c0r1 = cn; else c0r0 = cn;
        float hv = sigf(go) * tanhfast(cn);
        bf16 hb16 = __float2bfloat16(hv);
        unsigned hb = *(unsigned short*)&hb16;
        unsigned nb = (unsigned)__shfl_xor((int)hb, 1, 64);  // partner tid^1 = ul^1
        if (!(ul & 1)) {
          unsigned word = hb | (nb << 16);
          __hip_atomic_store((unsigned*)(h0out + row * H_ + ub + ul), word,
                             __ATOMIC_RELAXED, __HIP_MEMORY_SCOPE_AGENT);
        }
      }
    }
    __syncthreads();

    // ---- P4: L1-hh (hs=h1(s-2)) + H1 (hs, wh1s) ----
    if (doL1 && m == 1) {
#pragma unroll
      for (int strip = 0; strip < 4; ++strip) {
        f32x4 acc = (f32x4){0.f, 0.f, 0.f, 0.f};
#pragma unroll
        for (int kk = 0; kk < 16; ++kk) {
          short8 a = *(const short8*)&hs[strip * 16 + cl][q * 8 + kk * 32];
          acc = __builtin_amdgcn_mfma_f32_16x16x32_bf16(a, wl1[kk], acc, 0, 0, 0);
        }
#pragma unroll
        for (int r = 0; r < 4; ++r) S1[4 + g][strip * 16 + q * 4 + r][cl] = acc[r];
      }
    }
    if (doH1 && m == 0) {
      const int tH1 = s - 2;
      f32x4 aH = (f32x4){bh1v, bh1v, bh1v, bh1v};
      for (int kk = 0; kk < H_; kk += 32) {
        short8 a = *(const short8*)&hs[w * 16 + cl][q * 8 + kk];
        short8 b = *(const short8*)&wh1s[cl][q * 8 + kk];
        aH = __builtin_amdgcn_mfma_f32_16x16x32_bf16(a, b, aH, 0, 0, 0);
      }
      bf16* msl = mstage + (size_t)(tH1 & 3) * NBM + (size_t)n * B_ * M_;
#pragma unroll
      for (int r = 0; r < 4; ++r) {
        float v = aH[r];
        v = v > 0.f ? v : 0.2f * v;
        bf16 vb = __float2bfloat16(v);
        unsigned hb = *(unsigned short*)&vb;
        unsigned nb = (unsigned)__shfl_xor((int)hb, 1, 64);  // partner lane cl^1
        if (!(cl & 1)) {
          unsigned word = hb | (nb << 16);
          __hip_atomic_store((unsigned*)(msl + (w * 16 + q * 4 + r) * M_ + ub + cl),
                             word, __ATOMIC_RELAXED, __HIP_MEMORY_SCOPE_AGENT);
        }
      }
    }
    __syncthreads();

    // ---- P5: EW-L1 -> h1(s-1) sc1 stores ----
    if (doL1) {
      const int t = s - 1;
      bf16* h1out = h1buf + (size_t)(t & 1) * NBH + (size_t)n * B_ * H_;
#pragma unroll
      for (int it = 0; it < 2; ++it) {
        int e = tid + it * 512;
        int row = e >> 4, ul = e & 15;
        float gi = S1[0][row][ul] + S1[4][row][ul];
        float gf = S1[1][row][ul] + S1[5][row][ul];
        float gg = S1[2][row][ul] + S1[6][row][ul];
        float go = S1[3][row][ul] + S1[7][row][ul];
        float c = it ? c1r1 : c1r0;
        float cn = sigf(gf) * c + sigf(gi) * tanhfast(gg);
        if (it) c1r1 = cn; else c1r0 = cn;
        float hv = sigf(go) * tanhfast(cn);
        bf16 hb16 = __float2bfloat16(hv);
        unsigned hb = *(unsigned short*)&hb16;
        unsigned nb = (unsigned)__shfl_xor((int)hb, 1, 64);
        if (!(ul & 1)) {
          unsigned word = hb | (nb << 16);
          __hip_atomic_store((unsigned*)(h1out + row * H_ + ub + ul), word,
                             __ATOMIC_RELAXED, __HIP_MEMORY_SCOPE_AGENT);
        }
      }
    }
    // barrier drains every wave's vmcnt -> all sc1 data stores (h0 in P3,
    // mstage in P4, h1 here) are at the MALL before the flag store issues.
    __syncthreads();
    if (tid == 0)
      __hip_atomic_store(myflag, (unsigned)(s + 1), __ATOMIC_RELAXED,
                         __HIP_MEMORY_SCOPE_AGENT);

    // ================= barrier shadow =================
    // H2 (waves 4,5): mstage slot (s-3)&3, published at superstep s-1, read
    // via sc1 (MALL-direct). Next writer H1(s+3) is gated by our flag(s+2).
    if (doH2 && (w == 4 || w == 5)) {
      const int tH2 = s - 3;
      const int b = blk * 2 + (w - 4);
      const int o = lane & 7;
      const int oc = o < 7 ? o : 0;
      const int mc = (lane >> 3) * 64;
      const bf16* ms = mstage + (size_t)(tH2 & 3) * NBM + ((size_t)n * B_ + b) * M_ + mc;
      const float* w2p = Wh2 + (size_t)n * O_ * M_ + (size_t)oc * M_ + mc;
      float p = 0.f;
#pragma unroll
      for (int j = 0; j < 64; j += 8) {
        const unsigned long long* mp = (const unsigned long long*)(ms + j);
        unsigned long long u0 = __hip_atomic_load(mp,     __ATOMIC_RELAXED, __HIP_MEMORY_SCOPE_AGENT);
        unsigned long long u1 = __hip_atomic_load(mp + 1, __ATOMIC_RELAXED, __HIP_MEMORY_SCOPE_AGENT);
        float4 w0 = *(const float4*)(w2p + j);
        float4 w1 = *(const float4*)(w2p + j + 4);
        p += bfbits2f((unsigned short)(u0      )) * w0.x
           + bfbits2f((unsigned short)(u0 >> 16)) * w0.y
           + bfbits2f((unsigned short)(u0 >> 32)) * w0.z
           + bfbits2f((unsigned short)(u0 >> 48)) * w0.w
           + bfbits2f((unsigned short)(u1      )) * w1.x
           + bfbits2f((unsigned short)(u1 >> 16)) * w1.y
           + bfbits2f((unsigned short)(u1 >> 32)) * w1.z
           + bfbits2f((unsigned short)(u1 >> 48)) * w1.w;
      }
      p += __shfl_xor(p, 8, 64);
      p += __shfl_xor(p, 16, 64);
      p += __shfl_xor(p, 32, 64);
      if (lane < 7) {
        p += bh2[n * O_ + o];
        out[(((size_t)n * B_ + b) * T_ + tH2) * O_ + o] = p;
      }
    }

    // ---- poll (wave 7): relaxed sc1 loads; NO final fence (all cross-block
    // reads are sc1 MALL-direct). Periodic fence = liveness guard only. ----
    if (w == 7) {
      const unsigned tgt = (unsigned)(s + 1);
      unsigned* fp = pollbase + (lane & 31);
      int spins = 0;
      while (__hip_atomic_load(fp, __ATOMIC_RELAXED, __HIP_MEMORY_SCOPE_AGENT) < tgt) {
        __builtin_amdgcn_s_sleep(2);
        if (++spins >= 256) {
          spins = 0;
          __builtin_amdgcn_fence(__ATOMIC_ACQUIRE, "agent");
        }
      }
    }
    __syncthreads();
  }
}

extern "C" void kernel_launch(void* const* d_in, const int* in_sizes, int n_in,
                              void* d_out, int out_size, void* d_ws, size_t ws_size,
                              hipStream_t stream) {
  (void)in_sizes; (void)n_in; (void)out_size; (void)ws_size;
  const float* x    = (const float*)d_in[0];
  const float* Win  = (const float*)d_in[1];
  const float* bin  = (const float*)d_in[2];
  const float* Wih0 = (const float*)d_in[3];
  const float* Whh0 = (const float*)d_in[4];
  const float* bih0 = (const float*)d_in[5];
  const float* bhh0 = (const float*)d_in[6];
  const float* Wih1 = (const float*)d_in[7];
  const float* Whh1 = (const float*)d_in[8];
  const float* bih1 = (const float*)d_in[9];
  const float* bhh1 = (const float*)d_in[10];
  const float* Wh1  = (const float*)d_in[11];
  const float* bh1  = (const float*)d_in[12];
  const float* Wh2  = (const float*)d_in[13];
  const float* bh2  = (const float*)d_in[14];

  const size_t WLSTM = (size_t)N_ * G4_ * H_;
  const size_t WH1   = (size_t)N_ * M_ * H_;
  const size_t NFLAG = (size_t)N_ * 64;

  char* ws = (char*)d_ws;
  size_t off = 0;
  bf16* z      = (bf16*)(ws + off); off += (size_t)T_ * B_ * H_ * sizeof(bf16);
  bf16* Wih0b  = (bf16*)(ws + off); off += WLSTM * sizeof(bf16);
  bf16* Whh0b  = (bf16*)(ws + off); off += WLSTM * sizeof(bf16);
  bf16* Wih1b  = (bf16*)(ws + off); off += WLSTM * sizeof(bf16);
  bf16* Whh1b  = (bf16*)(ws + off); off += WLSTM * sizeof(bf16);
  bf16* Wh1b   = (bf16*)(ws + off); off += WH1 * sizeof(bf16);
  bf16* h0buf  = (bf16*)(ws + off); off += 2 * (size_t)N_ * B_ * H_ * sizeof(bf16);
  bf16* h1buf  = (bf16*)(ws + off); off += 2 * (size_t)N_ * B_ * H_ * sizeof(bf16);
  bf16* mstage = (bf16*)(ws + off); off += 4 * (size_t)N_ * B_ * M_ * sizeof(bf16);
  unsigned* flags = (unsigned*)(ws + off); off += NFLAG * sizeof(unsigned);

  // zero h/m state + flags (contiguous span)
  hipMemsetAsync(h0buf, 0, (char*)(flags + NFLAG) - (char*)h0buf, stream);

  cvt_kernel<<<dim3(2048), dim3(256), 0, stream>>>(Wih0, Wih0b, (int)(WLSTM / 4));
  cvt_kernel<<<dim3(2048), dim3(256), 0, stream>>>(Whh0, Whh0b, (int)(WLSTM / 4));
  cvt_kernel<<<dim3(2048), dim3(256), 0, stream>>>(Wih1, Wih1b, (int)(WLSTM / 4));
  cvt_kernel<<<dim3(2048), dim3(256), 0, stream>>>(Whh1, Whh1b, (int)(WLSTM / 4));
  cvt_kernel<<<dim3(1024), dim3(256), 0, stream>>>(Wh1, Wh1b, (int)(WH1 / 4));

  input_kernel<<<dim3(T_ * B_), dim3(256), 0, stream>>>(x, Win, bin, z);

  scan_kernel<<<dim3(256), dim3(512), 0, stream>>>(
      z, Wih0b, Whh0b, bih0, bhh0, Wih1b, Whh1b, bih1, bhh1,
      Wh1b, bh1, Wh2, bh2, h0buf, h1buf, mstage, (float*)d_out, flags);
}